// Round 2
// baseline (95.292 us; speedup 1.0000x reference)
//
#include <hip/hip_runtime.h>

// Problem constants (from reference setup_inputs): batch=4, seq=4096, dim=1024, fp32.
#define BATCH 4
#define SEQ   4096
#define DIM   1024
#define DIM4  (DIM / 4)      // 256 float4 lanes across dim
#define NC    512            // number of time chunks
#define CHUNK (SEQ / NC)     // 8 timesteps per chunk

__device__ __forceinline__ float4 f4_fma(float4 a, float4 h, float4 b) {
    float4 r;
    r.x = fmaf(a.x, h.x, b.x);
    r.y = fmaf(a.y, h.y, b.y);
    r.z = fmaf(a.z, h.z, b.z);
    r.w = fmaf(a.w, h.w, b.w);
    return r;
}

__device__ __forceinline__ float4 f4_mul(float4 a, float4 b) {
    float4 r;
    r.x = a.x * b.x;
    r.y = a.y * b.y;
    r.z = a.z * b.z;
    r.w = a.w * b.w;
    return r;
}

// Phase 1: per-(batch, chunk, dim4) summary of the chunk as an affine map
// h_out = P * h_in + Q   (P = prod of a over chunk, Q = local scan with h_in=0)
__global__ __launch_bounds__(256) void ssm_phase1(const float4* __restrict__ A,
                                                  const float4* __restrict__ B,
                                                  float4* __restrict__ P,
                                                  float4* __restrict__ Q) {
    const int c  = blockIdx.x % NC;
    const int b  = blockIdx.x / NC;
    const int d4 = threadIdx.x;   // 0..DIM4-1

    size_t base = ((size_t)b * SEQ + (size_t)c * CHUNK) * DIM4 + d4;

    float4 p = make_float4(1.f, 1.f, 1.f, 1.f);
    float4 q = make_float4(0.f, 0.f, 0.f, 0.f);

#pragma unroll
    for (int t = 0; t < CHUNK; ++t) {
        float4 a  = A[base + (size_t)t * DIM4];
        float4 bb = B[base + (size_t)t * DIM4];
        q = f4_fma(a, q, bb);
        p = f4_mul(p, a);
    }

    size_t w = ((size_t)b * NC + c) * DIM4 + d4;
    P[w] = p;
    Q[w] = q;
}

// Phase 2: Kogge-Stone scan over the NC chunk summaries per channel.
// One block per (batch, d4) channel; thread c owns chunk c.
// Writes carry-IN state for each chunk in place over P.
__global__ __launch_bounds__(NC) void ssm_phase2(float4* __restrict__ PH,   // in: P, out: carry-in H
                                                 const float4* __restrict__ Q) {
    const int b  = blockIdx.x / DIM4;
    const int d4 = blockIdx.x % DIM4;
    const int c  = threadIdx.x;      // chunk index 0..NC-1

    __shared__ float4 sp[NC];
    __shared__ float4 sq[NC];

    const size_t idx = ((size_t)b * NC + c) * DIM4 + d4;
    float4 p = PH[idx];
    float4 q = Q[idx];
    sp[c] = p;
    sq[c] = q;
    __syncthreads();

    // inclusive scan of affine maps: cur ∘ prev
    for (int off = 1; off < NC; off <<= 1) {
        float4 pp, qq;
        const bool has = (c >= off);
        if (has) { pp = sp[c - off]; qq = sq[c - off]; }
        __syncthreads();
        if (has) {
            q = f4_fma(p, qq, q);   // q = p_cur * q_prev + q_cur
            p = f4_mul(p, pp);      // p = p_cur * p_prev
            sp[c] = p;
            sq[c] = q;
        }
        __syncthreads();
    }

    // carry-in for chunk c = inclusive[c-1] applied to h0=0 -> its q component
    float4 h = (c == 0) ? make_float4(0.f, 0.f, 0.f, 0.f) : sq[c - 1];
    PH[idx] = h;
}

// Phase 3: re-run the recurrence per chunk seeded with its carry-in; emit y = c * h.
__global__ __launch_bounds__(256) void ssm_phase3(const float4* __restrict__ A,
                                                  const float4* __restrict__ B,
                                                  const float4* __restrict__ C,
                                                  const float4* __restrict__ H,
                                                  float4* __restrict__ Y) {
    const int c  = blockIdx.x % NC;
    const int b  = blockIdx.x / NC;
    const int d4 = threadIdx.x;

    size_t base = ((size_t)b * SEQ + (size_t)c * CHUNK) * DIM4 + d4;

    float4 h = H[((size_t)b * NC + c) * DIM4 + d4];

#pragma unroll
    for (int t = 0; t < CHUNK; ++t) {
        float4 a  = A[base + (size_t)t * DIM4];
        float4 bb = B[base + (size_t)t * DIM4];
        float4 cc = C[base + (size_t)t * DIM4];
        h = f4_fma(a, h, bb);
        Y[base + (size_t)t * DIM4] = f4_mul(cc, h);
    }
}

extern "C" void kernel_launch(void* const* d_in, const int* in_sizes, int n_in,
                              void* d_out, int out_size, void* d_ws, size_t ws_size,
                              hipStream_t stream) {
    // setup_inputs order: x (unused), B, C, A — all fp32 [4, 4096, 1024]
    const float* B = (const float*)d_in[1];
    const float* C = (const float*)d_in[2];
    const float* A = (const float*)d_in[3];
    float* Y = (float*)d_out;

    // Workspace: P (reused as carry H) then Q, each BATCH*NC*DIM floats = 8 MB.
    float* P = (float*)d_ws;
    float* Q = P + (size_t)BATCH * NC * DIM;

    ssm_phase1<<<BATCH * NC, 256, 0, stream>>>(
        (const float4*)A, (const float4*)B, (float4*)P, (float4*)Q);

    ssm_phase2<<<BATCH * DIM4, NC, 0, stream>>>(
        (float4*)P, (const float4*)Q);

    ssm_phase3<<<BATCH * NC, 256, 0, stream>>>(
        (const float4*)A, (const float4*)B, (const float4*)C,
        (const float4*)P, (float4*)Y);
}

// Round 3
// 95.027 us; speedup vs baseline: 1.0028x; 1.0028x over previous
//
#include <hip/hip_runtime.h>

// Problem constants (from reference setup_inputs): batch=4, seq=4096, dim=1024, fp32.
#define BATCH 4
#define SEQ   4096
#define DIM   1024
#define DIM4  (DIM / 4)      // 256 float4 lanes across dim
#define NC    512            // number of time chunks
#define CHUNK (SEQ / NC)     // 8 timesteps per chunk

__device__ __forceinline__ float4 f4_fma(float4 a, float4 h, float4 b) {
    float4 r;
    r.x = fmaf(a.x, h.x, b.x);
    r.y = fmaf(a.y, h.y, b.y);
    r.z = fmaf(a.z, h.z, b.z);
    r.w = fmaf(a.w, h.w, b.w);
    return r;
}

__device__ __forceinline__ float4 f4_mul(float4 a, float4 b) {
    float4 r;
    r.x = a.x * b.x;
    r.y = a.y * b.y;
    r.z = a.z * b.z;
    r.w = a.w * b.w;
    return r;
}

// Phase 1: per-(batch, chunk, dim4) summary of the chunk as an affine map
// h_out = P * h_in + Q   (P = prod of a over chunk, Q = local scan with h_in=0).
// All 16 loads are issued before any compute (explicit register batching for MLP).
__global__ __launch_bounds__(256, 4) void ssm_phase1(const float4* __restrict__ A,
                                                     const float4* __restrict__ B,
                                                     float4* __restrict__ P,
                                                     float4* __restrict__ Q) {
    const int c  = blockIdx.x % NC;
    const int b  = blockIdx.x / NC;
    const int d4 = threadIdx.x;   // 0..DIM4-1

    const size_t base = ((size_t)b * SEQ + (size_t)c * CHUNK) * DIM4 + d4;

    float4 av[CHUNK], bv[CHUNK];
#pragma unroll
    for (int t = 0; t < CHUNK; ++t) av[t] = A[base + (size_t)t * DIM4];
#pragma unroll
    for (int t = 0; t < CHUNK; ++t) bv[t] = B[base + (size_t)t * DIM4];

    float4 p = av[0];
    float4 q = bv[0];
#pragma unroll
    for (int t = 1; t < CHUNK; ++t) {
        q = f4_fma(av[t], q, bv[t]);
        p = f4_mul(p, av[t]);
    }

    const size_t w = ((size_t)b * NC + c) * DIM4 + d4;
    P[w] = p;
    Q[w] = q;
}

// Phase 2: Kogge-Stone scan over the NC chunk summaries per channel.
// One block per (batch, d4) channel; thread c owns chunk c.
// Writes carry-IN state for each chunk in place over P.
__global__ __launch_bounds__(NC) void ssm_phase2(float4* __restrict__ PH,   // in: P, out: carry-in H
                                                 const float4* __restrict__ Q) {
    const int b  = blockIdx.x / DIM4;
    const int d4 = blockIdx.x % DIM4;
    const int c  = threadIdx.x;      // chunk index 0..NC-1

    __shared__ float4 sp[NC];
    __shared__ float4 sq[NC];

    const size_t idx = ((size_t)b * NC + c) * DIM4 + d4;
    float4 p = PH[idx];
    float4 q = Q[idx];
    sp[c] = p;
    sq[c] = q;
    __syncthreads();

    // inclusive scan of affine maps: cur ∘ prev
    for (int off = 1; off < NC; off <<= 1) {
        float4 pp, qq;
        const bool has = (c >= off);
        if (has) { pp = sp[c - off]; qq = sq[c - off]; }
        __syncthreads();
        if (has) {
            q = f4_fma(p, qq, q);   // q = p_cur * q_prev + q_cur
            p = f4_mul(p, pp);      // p = p_cur * p_prev
            sp[c] = p;
            sq[c] = q;
        }
        __syncthreads();
    }

    // carry-in for chunk c = inclusive[c-1] applied to h0=0 -> its q component
    float4 h = (c == 0) ? make_float4(0.f, 0.f, 0.f, 0.f) : sq[c - 1];
    PH[idx] = h;
}

// Phase 3: re-run the recurrence per chunk seeded with its carry-in; emit y = c * h.
// All 25 loads issued before compute (explicit register batching for MLP).
__global__ __launch_bounds__(256, 4) void ssm_phase3(const float4* __restrict__ A,
                                                     const float4* __restrict__ B,
                                                     const float4* __restrict__ C,
                                                     const float4* __restrict__ H,
                                                     float4* __restrict__ Y) {
    const int c  = blockIdx.x % NC;
    const int b  = blockIdx.x / NC;
    const int d4 = threadIdx.x;

    const size_t base = ((size_t)b * SEQ + (size_t)c * CHUNK) * DIM4 + d4;

    float4 h = H[((size_t)b * NC + c) * DIM4 + d4];

    float4 av[CHUNK], bv[CHUNK], cv[CHUNK];
#pragma unroll
    for (int t = 0; t < CHUNK; ++t) av[t] = A[base + (size_t)t * DIM4];
#pragma unroll
    for (int t = 0; t < CHUNK; ++t) bv[t] = B[base + (size_t)t * DIM4];
#pragma unroll
    for (int t = 0; t < CHUNK; ++t) cv[t] = C[base + (size_t)t * DIM4];

#pragma unroll
    for (int t = 0; t < CHUNK; ++t) {
        h = f4_fma(av[t], h, bv[t]);
        Y[base + (size_t)t * DIM4] = f4_mul(cv[t], h);
    }
}

extern "C" void kernel_launch(void* const* d_in, const int* in_sizes, int n_in,
                              void* d_out, int out_size, void* d_ws, size_t ws_size,
                              hipStream_t stream) {
    // setup_inputs order: x (unused), B, C, A — all fp32 [4, 4096, 1024]
    const float* B = (const float*)d_in[1];
    const float* C = (const float*)d_in[2];
    const float* A = (const float*)d_in[3];
    float* Y = (float*)d_out;

    // Workspace: P (reused as carry H) then Q, each BATCH*NC*DIM floats = 8 MB.
    float* P = (float*)d_ws;
    float* Q = P + (size_t)BATCH * NC * DIM;

    ssm_phase1<<<BATCH * NC, 256, 0, stream>>>(
        (const float4*)A, (const float4*)B, (float4*)P, (float4*)Q);

    ssm_phase2<<<BATCH * DIM4, NC, 0, stream>>>(
        (float4*)P, (const float4*)Q);

    ssm_phase3<<<BATCH * NC, 256, 0, stream>>>(
        (const float4*)A, (const float4*)B, (const float4*)C,
        (const float4*)P, (float4*)Y);
}

// Round 5
// 94.865 us; speedup vs baseline: 1.0045x; 1.0017x over previous
//
#include <hip/hip_runtime.h>

// Problem constants (from reference setup_inputs): batch=4, seq=4096, dim=1024, fp32.
#define BATCH 4
#define SEQ   4096
#define DIM   1024
#define DIM4  (DIM / 4)      // 256 float4 lanes across dim
#define NC    512            // number of time chunks
#define CHUNK (SEQ / NC)     // 8 timesteps per chunk

#define SBAR() __builtin_amdgcn_sched_barrier(0)

typedef float nfloat4 __attribute__((ext_vector_type(4)));  // native vec for nontemporal builtin

__device__ __forceinline__ float4 f4_fma(float4 a, float4 h, float4 b) {
    float4 r;
    r.x = fmaf(a.x, h.x, b.x);
    r.y = fmaf(a.y, h.y, b.y);
    r.z = fmaf(a.z, h.z, b.z);
    r.w = fmaf(a.w, h.w, b.w);
    return r;
}

__device__ __forceinline__ float4 f4_mul(float4 a, float4 b) {
    float4 r;
    r.x = a.x * b.x;
    r.y = a.y * b.y;
    r.z = a.z * b.z;
    r.w = a.w * b.w;
    return r;
}

__device__ __forceinline__ void nt_store(float4 v, float4* p) {
    nfloat4 nv;
    nv.x = v.x; nv.y = v.y; nv.z = v.z; nv.w = v.w;
    __builtin_nontemporal_store(nv, reinterpret_cast<nfloat4*>(p));
}

// Phase 1: per-(batch, chunk, dim4) summary of the chunk as an affine map
// h_out = P * h_in + Q   (P = prod of a over chunk, Q = local scan with h_in=0).
// sched_barrier(0) pins all 16 loads BEFORE any compute so the scheduler
// cannot sink them back into the loop (round-2 failure mode: VGPR stayed 36).
__global__ __launch_bounds__(256) void ssm_phase1(const float4* __restrict__ A,
                                                  const float4* __restrict__ B,
                                                  float4* __restrict__ P,
                                                  float4* __restrict__ Q) {
    const int c  = blockIdx.x % NC;
    const int b  = blockIdx.x / NC;
    const int d4 = threadIdx.x;   // 0..DIM4-1

    const size_t base = ((size_t)b * SEQ + (size_t)c * CHUNK) * DIM4 + d4;

    float4 av[CHUNK], bv[CHUNK];
#pragma unroll
    for (int t = 0; t < CHUNK; ++t) av[t] = A[base + (size_t)t * DIM4];
#pragma unroll
    for (int t = 0; t < CHUNK; ++t) bv[t] = B[base + (size_t)t * DIM4];
    SBAR();   // all 16 global_load_dwordx4 issued; nothing may cross

    float4 p = av[0];
    float4 q = bv[0];
#pragma unroll
    for (int t = 1; t < CHUNK; ++t) {
        q = f4_fma(av[t], q, bv[t]);
        p = f4_mul(p, av[t]);
    }

    const size_t w = ((size_t)b * NC + c) * DIM4 + d4;
    P[w] = p;
    Q[w] = q;
}

// Phase 2: Kogge-Stone scan over the NC chunk summaries per channel.
// One block per (batch, d4) channel; thread c owns chunk c.
// Writes carry-IN state for each chunk in place over P.
__global__ __launch_bounds__(NC) void ssm_phase2(float4* __restrict__ PH,   // in: P, out: carry-in H
                                                 const float4* __restrict__ Q) {
    const int b  = blockIdx.x / DIM4;
    const int d4 = blockIdx.x % DIM4;
    const int c  = threadIdx.x;      // chunk index 0..NC-1

    __shared__ float4 sp[NC];
    __shared__ float4 sq[NC];

    const size_t idx = ((size_t)b * NC + c) * DIM4 + d4;
    float4 p = PH[idx];
    float4 q = Q[idx];
    sp[c] = p;
    sq[c] = q;
    __syncthreads();

    // inclusive scan of affine maps: cur ∘ prev
    for (int off = 1; off < NC; off <<= 1) {
        float4 pp, qq;
        const bool has = (c >= off);
        if (has) { pp = sp[c - off]; qq = sq[c - off]; }
        __syncthreads();
        if (has) {
            q = f4_fma(p, qq, q);   // q = p_cur * q_prev + q_cur
            p = f4_mul(p, pp);      // p = p_cur * p_prev
            sp[c] = p;
            sq[c] = q;
        }
        __syncthreads();
    }

    // carry-in for chunk c = inclusive[c-1] applied to h0=0 -> its q component
    float4 h = (c == 0) ? make_float4(0.f, 0.f, 0.f, 0.f) : sq[c - 1];
    PH[idx] = h;
}

// Phase 3: re-run the recurrence per chunk seeded with its carry-in; emit y = c * h.
// All 24+1 loads pinned before compute via sched_barrier; Y stored nontemporal
// (no reuse — keep A/B/C resident in L2/L3 instead).
__global__ __launch_bounds__(256) void ssm_phase3(const float4* __restrict__ A,
                                                  const float4* __restrict__ B,
                                                  const float4* __restrict__ C,
                                                  const float4* __restrict__ H,
                                                  float4* __restrict__ Y) {
    const int c  = blockIdx.x % NC;
    const int b  = blockIdx.x / NC;
    const int d4 = threadIdx.x;

    const size_t base = ((size_t)b * SEQ + (size_t)c * CHUNK) * DIM4 + d4;

    float4 h = H[((size_t)b * NC + c) * DIM4 + d4];

    float4 av[CHUNK], bv[CHUNK], cv[CHUNK];
#pragma unroll
    for (int t = 0; t < CHUNK; ++t) av[t] = A[base + (size_t)t * DIM4];
#pragma unroll
    for (int t = 0; t < CHUNK; ++t) bv[t] = B[base + (size_t)t * DIM4];
#pragma unroll
    for (int t = 0; t < CHUNK; ++t) cv[t] = C[base + (size_t)t * DIM4];
    SBAR();   // all 24 global_load_dwordx4 issued; nothing may cross

#pragma unroll
    for (int t = 0; t < CHUNK; ++t) {
        h = f4_fma(av[t], h, bv[t]);
        nt_store(f4_mul(cv[t], h), &Y[base + (size_t)t * DIM4]);
    }
}

extern "C" void kernel_launch(void* const* d_in, const int* in_sizes, int n_in,
                              void* d_out, int out_size, void* d_ws, size_t ws_size,
                              hipStream_t stream) {
    // setup_inputs order: x (unused), B, C, A — all fp32 [4, 4096, 1024]
    const float* B = (const float*)d_in[1];
    const float* C = (const float*)d_in[2];
    const float* A = (const float*)d_in[3];
    float* Y = (float*)d_out;

    // Workspace: P (reused as carry H) then Q, each BATCH*NC*DIM floats = 8 MB.
    float* P = (float*)d_ws;
    float* Q = P + (size_t)BATCH * NC * DIM;

    ssm_phase1<<<BATCH * NC, 256, 0, stream>>>(
        (const float4*)A, (const float4*)B, (float4*)P, (float4*)Q);

    ssm_phase2<<<BATCH * DIM4, NC, 0, stream>>>(
        (float4*)P, (const float4*)Q);

    ssm_phase3<<<BATCH * NC, 256, 0, stream>>>(
        (const float4*)A, (const float4*)B, (const float4*)C,
        (const float4*)P, (float4*)Y);
}

// Round 6
// 94.820 us; speedup vs baseline: 1.0050x; 1.0005x over previous
//
#include <hip/hip_runtime.h>

// Problem constants: batch=4, seq=4096, dim=1024, fp32.
#define BATCH 4
#define SEQ   4096
#define DIM   1024
#define DIM4  (DIM / 4)      // 256 float4 lanes across dim
#define NC    512            // number of time chunks
#define CHUNK (SEQ / NC)     // 8 timesteps per chunk
#define SLOTS 4              // chunk-slots per block (pipelined)
#define BPB   (NC / SLOTS)   // 128 blocks per batch

typedef float vf4 __attribute__((ext_vector_type(4)));

__device__ __forceinline__ vf4 vfma4(vf4 a, vf4 h, vf4 b) {
    vf4 r;
    r.x = fmaf(a.x, h.x, b.x);
    r.y = fmaf(a.y, h.y, b.y);
    r.z = fmaf(a.z, h.z, b.z);
    r.w = fmaf(a.w, h.w, b.w);
    return r;
}

// ---------------- Phase 1: chunk summaries (P = prod a, Q = local scan) ----------------
// 512 blocks x 4 slots, ping-pong double buffer. The single asm volatile with all 16
// chunk values as "+v" operands FORCES them live simultaneously (compiler cannot sink
// the loads - the round-3/5 failure mode where VGPR stayed 36).
__global__ __launch_bounds__(256, 1) void ssm_phase1(const vf4* __restrict__ gA,
                                                     const vf4* __restrict__ gB,
                                                     vf4* __restrict__ gP,
                                                     vf4* __restrict__ gQ) {
    const int j  = blockIdx.x;
    const int b  = j / BPB;
    const int c0 = (j % BPB) * SLOTS;
    const int d4 = threadIdx.x;

#define P1BASE(s) (((size_t)b * SEQ + (size_t)(c0 + (s)) * CHUNK) * DIM4 + d4)

#define P1LOAD(av, bv, s) do { const size_t _sb = P1BASE(s);                              \
    _Pragma("unroll") for (int t = 0; t < CHUNK; ++t) { av[t] = gA[_sb + (size_t)t * DIM4]; } \
    _Pragma("unroll") for (int t = 0; t < CHUNK; ++t) { bv[t] = gB[_sb + (size_t)t * DIM4]; } \
  } while (0)

#define PIN16(av, bv) asm volatile("" :                                                    \
    "+v"(av[0]), "+v"(av[1]), "+v"(av[2]), "+v"(av[3]),                                    \
    "+v"(av[4]), "+v"(av[5]), "+v"(av[6]), "+v"(av[7]),                                    \
    "+v"(bv[0]), "+v"(bv[1]), "+v"(bv[2]), "+v"(bv[3]),                                    \
    "+v"(bv[4]), "+v"(bv[5]), "+v"(bv[6]), "+v"(bv[7]))

#define P1COMP(av, bv, s) do {                                                             \
    vf4 p = av[0], q = bv[0];                                                              \
    _Pragma("unroll") for (int t = 1; t < CHUNK; ++t) { q = vfma4(av[t], q, bv[t]); p = p * av[t]; } \
    const size_t _w = ((size_t)b * NC + (size_t)(c0 + (s))) * DIM4 + d4;                   \
    gP[_w] = p; gQ[_w] = q;                                                                \
  } while (0)

    vf4 a0[CHUNK], b0[CHUNK], a1[CHUNK], b1[CHUNK];

    P1LOAD(a0, b0, 0);
    P1LOAD(a1, b1, 1);
    PIN16(a0, b0);  P1COMP(a0, b0, 0);
    P1LOAD(a0, b0, 2);
    PIN16(a1, b1);  P1COMP(a1, b1, 1);
    P1LOAD(a1, b1, 3);
    PIN16(a0, b0);  P1COMP(a0, b0, 2);
    PIN16(a1, b1);  P1COMP(a1, b1, 3);

#undef P1BASE
#undef P1LOAD
#undef PIN16
#undef P1COMP
}

// ---------------- Phase 2: Kogge-Stone scan over NC chunk summaries per channel --------
__global__ __launch_bounds__(NC) void ssm_phase2(vf4* __restrict__ PH,   // in: P, out: carry-in H
                                                 const vf4* __restrict__ Q) {
    const int b  = blockIdx.x / DIM4;
    const int d4 = blockIdx.x % DIM4;
    const int c  = threadIdx.x;      // chunk index 0..NC-1

    __shared__ vf4 sp[NC];
    __shared__ vf4 sq[NC];

    const size_t idx = ((size_t)b * NC + c) * DIM4 + d4;
    vf4 p = PH[idx];
    vf4 q = Q[idx];
    sp[c] = p;
    sq[c] = q;
    __syncthreads();

    for (int off = 1; off < NC; off <<= 1) {
        vf4 pp, qq;
        const bool has = (c >= off);
        if (has) { pp = sp[c - off]; qq = sq[c - off]; }
        __syncthreads();
        if (has) {
            q = vfma4(p, qq, q);   // q = p_cur * q_prev + q_cur
            p = p * pp;            // p = p_cur * p_prev
            sp[c] = p;
            sq[c] = q;
        }
        __syncthreads();
    }

    vf4 h = (c == 0) ? (vf4)(0.f) : sq[c - 1];
    PH[idx] = h;
}

// ---------------- Phase 3: seeded re-scan, y = c * h ----------------
__global__ __launch_bounds__(256, 1) void ssm_phase3(const vf4* __restrict__ gA,
                                                     const vf4* __restrict__ gB,
                                                     const vf4* __restrict__ gC,
                                                     const vf4* __restrict__ gH,
                                                     vf4* __restrict__ gY) {
    const int j  = blockIdx.x;
    const int b  = j / BPB;
    const int c0 = (j % BPB) * SLOTS;
    const int d4 = threadIdx.x;

#define P3BASE(s) (((size_t)b * SEQ + (size_t)(c0 + (s)) * CHUNK) * DIM4 + d4)

#define P3LOAD(av, bv, cv, hh, s) do { const size_t _sb = P3BASE(s);                       \
    _Pragma("unroll") for (int t = 0; t < CHUNK; ++t) { av[t] = gA[_sb + (size_t)t * DIM4]; } \
    _Pragma("unroll") for (int t = 0; t < CHUNK; ++t) { bv[t] = gB[_sb + (size_t)t * DIM4]; } \
    _Pragma("unroll") for (int t = 0; t < CHUNK; ++t) { cv[t] = gC[_sb + (size_t)t * DIM4]; } \
    hh = gH[((size_t)b * NC + (size_t)(c0 + (s))) * DIM4 + d4];                            \
  } while (0)

#define PIN25(av, bv, cv, hh) asm volatile("" :                                            \
    "+v"(av[0]), "+v"(av[1]), "+v"(av[2]), "+v"(av[3]),                                    \
    "+v"(av[4]), "+v"(av[5]), "+v"(av[6]), "+v"(av[7]),                                    \
    "+v"(bv[0]), "+v"(bv[1]), "+v"(bv[2]), "+v"(bv[3]),                                    \
    "+v"(bv[4]), "+v"(bv[5]), "+v"(bv[6]), "+v"(bv[7]),                                    \
    "+v"(cv[0]), "+v"(cv[1]), "+v"(cv[2]), "+v"(cv[3]),                                    \
    "+v"(cv[4]), "+v"(cv[5]), "+v"(cv[6]), "+v"(cv[7]),                                    \
    "+v"(hh))

#define P3COMP(av, bv, cv, hh, s) do { const size_t _sb = P3BASE(s); vf4 h = hh;           \
    _Pragma("unroll") for (int t = 0; t < CHUNK; ++t) {                                    \
        h = vfma4(av[t], h, bv[t]);                                                        \
        __builtin_nontemporal_store(cv[t] * h, &gY[_sb + (size_t)t * DIM4]);               \
    } } while (0)

    vf4 a0[CHUNK], b0[CHUNK], cc0[CHUNK], h0;
    vf4 a1[CHUNK], b1[CHUNK], cc1[CHUNK], h1;

    P3LOAD(a0, b0, cc0, h0, 0);
    P3LOAD(a1, b1, cc1, h1, 1);
    PIN25(a0, b0, cc0, h0);  P3COMP(a0, b0, cc0, h0, 0);
    P3LOAD(a0, b0, cc0, h0, 2);
    PIN25(a1, b1, cc1, h1);  P3COMP(a1, b1, cc1, h1, 1);
    P3LOAD(a1, b1, cc1, h1, 3);
    PIN25(a0, b0, cc0, h0);  P3COMP(a0, b0, cc0, h0, 2);
    PIN25(a1, b1, cc1, h1);  P3COMP(a1, b1, cc1, h1, 3);

#undef P3BASE
#undef P3LOAD
#undef PIN25
#undef P3COMP
}

extern "C" void kernel_launch(void* const* d_in, const int* in_sizes, int n_in,
                              void* d_out, int out_size, void* d_ws, size_t ws_size,
                              hipStream_t stream) {
    // setup_inputs order: x (unused), B, C, A — all fp32 [4, 4096, 1024]
    const vf4* B = (const vf4*)d_in[1];
    const vf4* C = (const vf4*)d_in[2];
    const vf4* A = (const vf4*)d_in[3];
    vf4* Y = (vf4*)d_out;

    // Workspace: P (reused as carry H) then Q, each BATCH*NC*DIM floats = 8 MB.
    vf4* P = (vf4*)d_ws;
    vf4* Q = P + (size_t)BATCH * NC * DIM4;

    ssm_phase1<<<BATCH * BPB, 256, 0, stream>>>(A, B, P, Q);

    ssm_phase2<<<BATCH * DIM4, NC, 0, stream>>>(P, Q);

    ssm_phase3<<<BATCH * BPB, 256, 0, stream>>>(A, B, C, P, Y);
}